// Round 5
// baseline (1084.722 us; speedup 1.0000x reference)
//
#include <hip/hip_runtime.h>
#include <math.h>

#define B_      4
#define C_      32
#define COND_   80
#define LMEL_   2048
#define HOP_    8
#define UP_     8
#define LAYERS_ 4
#define K_      3
#define HID_    64
#define KPK_    3
#define EMB_    512
#define LAUD_   (LMEL_*UP_)          // 16384
#define KCH_    (LAYERS_*C_*2*C_*K_) // 24576
#define BCH_    (LAYERS_*2*C_)       // 256

typedef short v8s __attribute__((ext_vector_type(8)));
typedef float v4f __attribute__((ext_vector_type(4)));

__device__ __forceinline__ float lrelu_(float v, float s) { return v >= 0.f ? v : s * v; }

__device__ __forceinline__ unsigned short f2bf(float f) {  // RNE float->bf16
  unsigned int x = __float_as_uint(f);
  unsigned int r = (x + 0x7FFFu + ((x >> 16) & 1u)) >> 16;
  return (unsigned short)r;
}

// ---------------------------------------------------------------- prep: generic slab transpose src[s][oc][ick] -> dst[s][ick][oc]
__global__ void k_mkWTs(const float* __restrict__ src, float* __restrict__ dst,
                        int S, int OC, int ICK) {
  int idx = blockIdx.x*256 + threadIdx.x;
  if (idx >= S*OC*ICK) return;
  int s = idx / (OC*ICK), rem = idx % (OC*ICK);
  int oc = rem / ICK, ick = rem % ICK;
  dst[s*OC*ICK + ick*OC + oc] = src[idx];
}

// ---------------------------------------------------------------- K1: noise + condition
__global__ void k_noise_cond(const float* __restrict__ ne, const float* __restrict__ fw,
                             const float* __restrict__ fb, const float* __restrict__ c,
                             float* __restrict__ cond) {
  int b = blockIdx.x / COND_;
  int cc = blockIdx.x % COND_;
  __shared__ float red[256];
  float p = 0.f;
  for (int j = threadIdx.x; j < EMB_; j += 256)
    p += ne[b*EMB_ + j] * fw[cc*EMB_ + j];
  red[threadIdx.x] = p;
  __syncthreads();
  for (int s = 128; s > 0; s >>= 1) {
    if (threadIdx.x < s) red[threadIdx.x] += red[threadIdx.x + s];
    __syncthreads();
  }
  float noise = red[0] + fb[cc];
  const float* cp = c + (b*COND_ + cc)*LMEL_;
  float* op = cond + (b*COND_ + cc)*LMEL_;
  for (int l = threadIdx.x; l < LMEL_; l += 256) op[l] = cp[l] + noise;
}

// ---------------------------------------------------------------- K2: KP input conv (80->64, k=5, pad=2, lrelu 0.1), T=32, wT[(cc*5+k)*64+ch]
__global__ __launch_bounds__(256) void k_kp_in(const float* __restrict__ cond, const float* __restrict__ wT,
                                               const float* __restrict__ bias, float* __restrict__ out) {
  const int T = 32;
  int b  = blockIdx.x / (LMEL_/T);
  int lb = (blockIdx.x % (LMEL_/T)) * T;
  __shared__ float sc[COND_][T + 4];
  for (int idx = threadIdx.x; idx < COND_*(T+4); idx += 256) {
    int cc = idx / (T+4), j = idx % (T+4);
    int l = lb + j - 2;
    sc[cc][j] = (l >= 0 && l < LMEL_) ? cond[(b*COND_ + cc)*LMEL_ + l] : 0.f;
  }
  __syncthreads();
  int ch = threadIdx.x & 63;
  int lq = threadIdx.x >> 6;  // 0..3, 8 l's each
  float acc[8];
#pragma unroll
  for (int ii = 0; ii < 8; ii++) acc[ii] = bias[ch];
  for (int cc = 0; cc < COND_; cc++) {
    float r[12];
#pragma unroll
    for (int j = 0; j < 12; j++) r[j] = sc[cc][lq*8 + j];
#pragma unroll
    for (int k = 0; k < 5; k++) {
      float wv = wT[(cc*5 + k)*64 + ch];
#pragma unroll
      for (int ii = 0; ii < 8; ii++) acc[ii] = fmaf(wv, r[ii + k], acc[ii]);
    }
  }
  float* op = out + (b*HID_ + ch)*LMEL_ + lb + lq*8;
#pragma unroll
  for (int ii = 0; ii < 8; ii++) acc[ii] = lrelu_(acc[ii], 0.1f);
  *reinterpret_cast<float4*>(&op[0]) = make_float4(acc[0], acc[1], acc[2], acc[3]);
  *reinterpret_cast<float4*>(&op[4]) = make_float4(acc[4], acc[5], acc[6], acc[7]);
}

// ---------------------------------------------------------------- K3: fused res pair: out = in + lrelu(conv2(lrelu(conv1(in))))
// w1T/w2T: [(cc*3+k)*64 + ch]
__global__ __launch_bounds__(256) void k_kp_res2(const float* __restrict__ in,
                                                 const float* __restrict__ w1T, const float* __restrict__ b1,
                                                 const float* __restrict__ w2T, const float* __restrict__ b2,
                                                 float* __restrict__ out) {
  const int T = 32;
  int b  = blockIdx.x / (LMEL_/T);
  int lb = (blockIdx.x % (LMEL_/T)) * T;
  __shared__ float si[HID_][38];   // cols lb-2 .. lb+33 (36 used)
  __shared__ float sr[HID_][38];   // intermediate r, cols lb-1 .. lb+32 (34 used)
  for (int idx = threadIdx.x; idx < HID_*36; idx += 256) {
    int cc = idx / 36, j = idx % 36;
    int l = lb - 2 + j;
    si[cc][j] = (l >= 0 && l < LMEL_) ? in[(b*HID_ + cc)*LMEL_ + l] : 0.f;
  }
  __syncthreads();
  int ch = threadIdx.x & 63;
  int lq = threadIdx.x >> 6;   // 0..3
  // stage 1: r[m] for m = lq*9 .. lq*9+8 (m < 34), si cols m..m+2
  {
    float b1v = b1[ch];
    float a1[9];
#pragma unroll
    for (int jj = 0; jj < 9; jj++) a1[jj] = b1v;
    for (int cc = 0; cc < HID_; cc++) {
      float r[11];
#pragma unroll
      for (int j = 0; j < 11; j++) r[j] = si[cc][lq*9 + j];
#pragma unroll
      for (int k = 0; k < 3; k++) {
        float wv = w1T[(cc*3 + k)*64 + ch];
#pragma unroll
        for (int jj = 0; jj < 9; jj++) a1[jj] = fmaf(wv, r[jj + k], a1[jj]);
      }
    }
#pragma unroll
    for (int jj = 0; jj < 9; jj++) {
      int m = lq*9 + jj;
      if (m < 34) sr[ch][m] = lrelu_(a1[jj], 0.1f);
    }
  }
  __syncthreads();
  // stage 2: out[n] = si[n+2] + lrelu(conv2(sr)[n]), n = lq*8 .. lq*8+7
  {
    float b2v = b2[ch];
    float a2[8];
#pragma unroll
    for (int jj = 0; jj < 8; jj++) a2[jj] = b2v;
    for (int cc = 0; cc < HID_; cc++) {
      float r[10];
#pragma unroll
      for (int j = 0; j < 10; j++) r[j] = sr[cc][lq*8 + j];
#pragma unroll
      for (int k = 0; k < 3; k++) {
        float wv = w2T[(cc*3 + k)*64 + ch];
#pragma unroll
        for (int jj = 0; jj < 8; jj++) a2[jj] = fmaf(wv, r[jj + k], a2[jj]);
      }
    }
    float* op = out + (b*HID_ + ch)*LMEL_ + lb + lq*8;
    float v[8];
#pragma unroll
    for (int jj = 0; jj < 8; jj++)
      v[jj] = si[ch][lq*8 + jj + 2] + lrelu_(a2[jj], 0.1f);
    *reinterpret_cast<float4*>(&op[0]) = make_float4(v[0], v[1], v[2], v[3]);
    *reinterpret_cast<float4*>(&op[4]) = make_float4(v[4], v[5], v[6], v[7]);
  }
}

// ---------------------------------------------------------------- K4: bias conv (64->256, k=3, pad=1), T=16, wT[(cc*3+k)*256+ch]
__global__ __launch_bounds__(256) void k_kp_bias(const float* __restrict__ in, const float* __restrict__ wT,
                                                 const float* __restrict__ bias, float* __restrict__ out) {
  const int T = 16;
  int b  = blockIdx.x / (LMEL_/T);
  int lb = (blockIdx.x % (LMEL_/T)) * T;
  __shared__ float si[HID_][T + 2];
  for (int idx = threadIdx.x; idx < HID_*(T+2); idx += 256) {
    int cc = idx / (T+2), j = idx % (T+2);
    int l = lb + j - 1;
    si[cc][j] = (l >= 0 && l < LMEL_) ? in[(b*HID_ + cc)*LMEL_ + l] : 0.f;
  }
  __syncthreads();
  int ch = threadIdx.x;  // 0..255
  float acc[T];
  float bv = bias[ch];
#pragma unroll
  for (int ii = 0; ii < T; ii++) acc[ii] = bv;
  for (int cc = 0; cc < HID_; cc++) {
    float w0 = wT[(cc*3 + 0)*256 + ch];
    float w1 = wT[(cc*3 + 1)*256 + ch];
    float w2 = wT[(cc*3 + 2)*256 + ch];
#pragma unroll
    for (int ii = 0; ii < T; ii++)
      acc[ii] = fmaf(w0, si[cc][ii], fmaf(w1, si[cc][ii+1], fmaf(w2, si[cc][ii+2], acc[ii])));
  }
  float* op = out + (b*BCH_ + ch)*LMEL_ + lb;
#pragma unroll
  for (int q = 0; q < 4; q++)
    *reinterpret_cast<float4*>(&op[q*4]) = make_float4(acc[q*4], acc[q*4+1], acc[q*4+2], acc[q*4+3]);
}

// ---------------------------------------------------------------- prep: upsample weight transpose -> wt[(ci*16+j)*32+co]
__global__ void k_mkUp(const float* __restrict__ upw, float* __restrict__ wt) {
  int idx = blockIdx.x*256 + threadIdx.x;
  if (idx >= C_*C_*16) return;
  int co = idx & 31, j = (idx >> 5) & 15, ci = idx >> 9;
  wt[idx] = upw[(ci*C_ + co)*16 + j];
}

// ---------------------------------------------------------------- K5: upsample (conv_transpose1d stride 8, k=16, pad=4), lrelu(x,0.2) input
#define UT 32
__global__ __launch_bounds__(256) void k_upsample(const float* __restrict__ x, const float* __restrict__ wt,
                                                  float* __restrict__ h) {
  int b  = blockIdx.x / 65;
  int s0 = (blockIdx.x % 65) * UT;
  __shared__ float sw[16384];          // [ci][j][co]
  __shared__ float sx[C_][33 + 3];
  for (int idx = threadIdx.x*4; idx < 16384; idx += 1024)
    *reinterpret_cast<float4*>(&sw[idx]) = *reinterpret_cast<const float4*>(&wt[idx]);
  for (int idx = threadIdx.x; idx < C_*33; idx += 256) {
    int ci = idx / 33, i = idx % 33;
    int s = s0 - 1 + i;
    float v = (s >= 0 && s < LMEL_) ? x[(b*C_ + ci)*LMEL_ + s] : 0.f;
    sx[ci][i] = lrelu_(v, 0.2f);
  }
  __syncthreads();
  int co = threadIdx.x & 31, sq = threadIdx.x >> 5;  // sq 0..7, 4 frames each
  float acc[4][8];
#pragma unroll
  for (int k = 0; k < 4; k++)
#pragma unroll
    for (int r = 0; r < 8; r++) acc[k][r] = 0.f;
  for (int ci = 0; ci < C_; ci++) {
    float xv[5];
#pragma unroll
    for (int m = 0; m < 5; m++) xv[m] = sx[ci][sq*4 + m];
    const float* wl = &sw[ci*512 + co];
#pragma unroll
    for (int r = 0; r < 8; r++) {
      float wa = wl[r*32];
      float wb = wl[(r+8)*32];
#pragma unroll
      for (int k = 0; k < 4; k++)
        acc[k][r] = fmaf(wa, xv[k+1], fmaf(wb, xv[k], acc[k][r]));
    }
  }
  float* op = h + ((size_t)b*C_ + co)*LAUD_;
#pragma unroll
  for (int k = 0; k < 4; k++) {
    int s1 = s0 + sq*4 + k;
    int lo = 8*s1 - 4;
    if (lo >= 0 && lo + 4 <= LAUD_)
      *reinterpret_cast<float4*>(&op[lo]) = make_float4(acc[k][0], acc[k][1], acc[k][2], acc[k][3]);
    if (lo >= -4 && lo + 8 <= LAUD_)
      *reinterpret_cast<float4*>(&op[lo+4]) = make_float4(acc[k][4], acc[k][5], acc[k][6], acc[k][7]);
  }
}

// ---------------------------------------------------------------- prep: A-fragment-ordered bf16 weights
__global__ void k_mkA(const float* __restrict__ kw, unsigned short* __restrict__ waf) {
  int idx = blockIdx.x*256 + threadIdx.x;
  if (idx >= KCH_*HID_*KPK_) return;   // 4,718,592
  int i    = idx & 7;
  int lane = (idx >> 3) & 63;
  int ks   = (idx >> 9) % 6;
  int tile = (idx / 3072) & 3;
  int rk   = idx / 12288;              // 0..383
  int layer = rk / 96, rem = rk % 96, ci = rem / 3, kk = rem % 3;
  int cout = tile*16 + (lane & 15);
  int j    = ks*32 + ((lane >> 4) << 3) + i;
  int row  = ((layer*32 + ci)*64 + cout)*3 + kk;
  waf[idx] = f2bf(kw[row*192 + j]);
}

// ---------------------------------------------------------------- prep: kernel-conv bias reordered
__global__ void k_mkKbT(const float* __restrict__ kb, float* __restrict__ kbt) {
  int idx = blockIdx.x*256 + threadIdx.x;
  if (idx >= KCH_) return;             // 24576
  int cr = idx & 15, tile = (idx >> 4) & 3, rk = idx >> 6;
  int layer = rk / 96, rem = rk % 96, ci = rem / 3, kk = rem % 3;
  int cout = tile*16 + cr;
  kbt[idx] = kb[((layer*32 + ci)*64 + cout)*3 + kk];
}

// ---------------------------------------------------------------- K6: dilated conv (32->32, k=3) on lrelu(h+ad,0.2), out lrelu 0.2, T=128
// wT[(ci*3+k)*32 + co]
template<int DIL>
__global__ __launch_bounds__(256) void k_dilconv(const float* __restrict__ h, const float* __restrict__ ad,
                                                 const float* __restrict__ wT, float* __restrict__ y2) {
  const int T = 128;
  int b  = blockIdx.x / (LAUD_/T);
  int tb = (blockIdx.x % (LAUD_/T)) * T;
  const int W = T + 2*DIL;
  __shared__ float ss[C_][T + 2*27 + 4];
  for (int idx = threadIdx.x; idx < C_*W; idx += 256) {
    int ci = idx / W, j = idx % W;
    int t = tb - DIL + j;
    float v = 0.f;
    if (t >= 0 && t < LAUD_) {
      int g = (b*C_ + ci)*LAUD_ + t;
      v = h[g] + ad[g];
    }
    ss[ci][j] = lrelu_(v, 0.2f);
  }
  __syncthreads();
  int co = threadIdx.x & 31, tq = threadIdx.x >> 5;
  float acc[16];
#pragma unroll
  for (int ii = 0; ii < 16; ii++) acc[ii] = 0.f;
  for (int ci = 0; ci < C_; ci++) {
    float w0 = wT[(ci*3 + 0)*32 + co];
    float w1 = wT[(ci*3 + 1)*32 + co];
    float w2 = wT[(ci*3 + 2)*32 + co];
#pragma unroll
    for (int ii = 0; ii < 16; ii++) {
      int tl = tq*16 + ii;
      acc[ii] = fmaf(w0, ss[ci][tl], fmaf(w1, ss[ci][tl + DIL], fmaf(w2, ss[ci][tl + 2*DIL], acc[ii])));
    }
  }
  float* op = y2 + (b*C_ + co)*LAUD_ + tb + tq*16;
#pragma unroll
  for (int ii = 0; ii < 16; ii++) acc[ii] = lrelu_(acc[ii], 0.2f);
#pragma unroll
  for (int q = 0; q < 4; q++)
    *reinterpret_cast<float4*>(&op[q*4]) = make_float4(acc[q*4], acc[q*4+1], acc[q*4+2], acc[q*4+3]);
}

// ---------------------------------------------------------------- K7: MFMA-fused KP-GEMM + LVC + gate + h update
// 16 waves (1024 thr): wave = wq*4 + tile; wq = ci-quarter (8 ci), tile = 16 couts.
// sy skewed (col += 4*(col>>5)) -> 2-way banks; red aliases sy (sync-separated).
#define FR2 32
#define SYC(c) ((c) + (((c) >> 5) << 2))
#define RED(t, l, rs) pool[(((t)*64 + (l))*33) + (rs)]

#define EPILOGUE(G, OO)                                                          \
  {                                                                              \
    __syncthreads();                                                             \
    if (wq == 3) {                                                               \
      _Pragma("unroll") for (int r = 0; r < 4; r++)                              \
        _Pragma("unroll") for (int s = 0; s < 8; s++)                            \
          RED(tile, lane, r*8 + s) = OO[r][s];                                   \
    }                                                                            \
    __syncthreads();                                                             \
    if (wq == 2) {                                                               \
      _Pragma("unroll") for (int r = 0; r < 4; r++)                              \
        _Pragma("unroll") for (int s = 0; s < 8; s++)                            \
          RED(tile, lane, r*8 + s) += OO[r][s];                                  \
    }                                                                            \
    __syncthreads();                                                             \
    if (wq == 1) {                                                               \
      _Pragma("unroll") for (int r = 0; r < 4; r++)                              \
        _Pragma("unroll") for (int s = 0; s < 8; s++)                            \
          RED(tile, lane, r*8 + s) += OO[r][s];                                  \
    }                                                                            \
    __syncthreads();                                                             \
    if (wq == 0) {                                                               \
      _Pragma("unroll") for (int r = 0; r < 4; r++) {                            \
        int cout = tile*16 + ((lane >> 4) << 2) + r;                             \
        float bv = biasb[((size_t)b*BCH_ + layer*2*C_ + cout)*LMEL_ + l0 + G*16 + f]; \
        _Pragma("unroll") for (int s = 0; s < 8; s++)                            \
          OO[r][s] += RED(tile, lane, r*8 + s) + bv;                             \
      }                                                                          \
      if (tile >= 2) {                                                           \
        _Pragma("unroll") for (int r = 0; r < 4; r++)                            \
          _Pragma("unroll") for (int s = 0; s < 8; s++)                          \
            RED(tile, lane, r*8 + s) = OO[r][s];                                 \
      }                                                                          \
    }                                                                            \
    __syncthreads();                                                             \
    if (wave < 2) {                                                              \
      _Pragma("unroll") for (int r = 0; r < 4; r++) {                            \
        int cout = tile*16 + ((lane >> 4) << 2) + r;                             \
        size_t base = ((size_t)b*C_ + cout)*LAUD_ + (size_t)(l0 + G*16 + f)*HOP_;\
        float4 h0 = *reinterpret_cast<const float4*>(&h[base]);                  \
        float4 h1 = *reinterpret_cast<const float4*>(&h[base + 4]);              \
        float4 a0 = *reinterpret_cast<const float4*>(&ad[base]);                 \
        float4 a1 = *reinterpret_cast<const float4*>(&ad[base + 4]);             \
        float outv[8];                                                           \
        _Pragma("unroll") for (int s = 0; s < 8; s++) {                          \
          float v  = OO[r][s];                                                   \
          float tv = RED(tile + 2, lane, r*8 + s);                               \
          float sig = 1.f / (1.f + __expf(-v));                                  \
          float th  = 1.f - 2.f / (1.f + __expf(2.f*tv));                        \
          float hv = (s < 4) ? ((const float*)&h0)[s] : ((const float*)&h1)[s-4];\
          float av = (s < 4) ? ((const float*)&a0)[s] : ((const float*)&a1)[s-4];\
          outv[s] = hv + av + sig * th;                                          \
        }                                                                        \
        *reinterpret_cast<float4*>(&h[base])     = make_float4(outv[0], outv[1], outv[2], outv[3]); \
        *reinterpret_cast<float4*>(&h[base + 4]) = make_float4(outv[4], outv[5], outv[6], outv[7]); \
      }                                                                          \
    }                                                                            \
  }

__global__ __launch_bounds__(1024) void k_lvc_mfma(
    const float* __restrict__ hkp, const unsigned short* __restrict__ waf,
    const float* __restrict__ kbt, const float* __restrict__ biasb,
    const float* __restrict__ y2, const float* __restrict__ ad,
    float* __restrict__ h, int layer) {
  int b  = blockIdx.x >> 6;               // 64 frame-tiles of 32
  int l0 = (blockIdx.x & 63) * FR2;

  __shared__ __align__(16) float pool[32*292];             // sy (skewed) / red alias
  __shared__ __align__(16) float shh[HID_][36];            // 34 used
  __shared__ __align__(16) unsigned short FB[2*6*64*8];    // B frags, 2 tiles x 6 ksteps

  int tid = threadIdx.x;
  for (int idx = tid; idx < C_*(FR2*HOP_+2); idx += 1024) {
    int ci = idx / (FR2*HOP_+2), j = idx % (FR2*HOP_+2);
    int t = l0*HOP_ - 1 + j;
    pool[ci*292 + SYC(j)] = (t >= 0 && t < LAUD_) ? y2[(b*C_ + ci)*LAUD_ + t] : 0.f;
  }
  for (int idx = tid; idx < HID_*34; idx += 1024) {
    int hh = idx / 34, j = idx % 34;
    int l = l0 - 1 + j;
    shh[hh][j] = (l >= 0 && l < LMEL_) ? hkp[(b*HID_ + hh)*LMEL_ + l] : 0.f;
  }
  __syncthreads();
  // build B fragments for both 16-frame sub-tiles
  for (int idx = tid; idx < 6144; idx += 1024) {
    int i = idx & 7, lane2 = (idx >> 3) & 63, gk = idx >> 9;  // gk = g*6+ks
    int ks = gk % 6, g = gk / 6;
    int k = ks*32 + ((lane2 >> 4) << 3) + i;
    int col = lane2 & 15;
    int hh = k / 3, q = k - hh*3;
    FB[idx] = f2bf(shh[hh][g*16 + col + q]);
  }
  __syncthreads();

  int wave = tid >> 6, lane = tid & 63;
  int tile = wave & 3, wq = wave >> 2;    // wq = ci-quarter
  int f = lane & 15;

  v8s bfrA[6], bfrB[6];
#pragma unroll
  for (int ks = 0; ks < 6; ks++) {
    bfrA[ks] = *reinterpret_cast<const v8s*>(&FB[(ks*64 + lane)*8]);
    bfrB[ks] = *reinterpret_cast<const v8s*>(&FB[((6 + ks)*64 + lane)*8]);
  }

  float o0[4][8], o1[4][8];
#pragma unroll
  for (int r = 0; r < 4; r++)
#pragma unroll
    for (int s = 0; s < 8; s++) { o0[r][s] = 0.f; o1[r][s] = 0.f; }

  const int rk0 = layer*96 + wq*24;       // 8 ci per quarter = 24 rk
  const unsigned short* wbase = waf + ((size_t)rk0*4 + tile)*3072 + lane*8;
  const float* kbbase = kbt + (rk0*4 + tile)*16 + ((lane >> 4) << 2);

  for (int ciq = 0; ciq < 8; ciq++) {
    int ci = wq*8 + ciq;
    const float* syrow = &pool[ci*292];
    float syr0[12], syr1[12];
    {
      int c0 = f*8, c1 = 128 + f*8;
      float4 s0 = *reinterpret_cast<const float4*>(&syrow[SYC(c0)]);
      float4 s1 = *reinterpret_cast<const float4*>(&syrow[SYC(c0+4)]);
      float4 s2 = *reinterpret_cast<const float4*>(&syrow[SYC(c0+8)]);
      syr0[0]=s0.x; syr0[1]=s0.y; syr0[2]=s0.z; syr0[3]=s0.w;
      syr0[4]=s1.x; syr0[5]=s1.y; syr0[6]=s1.z; syr0[7]=s1.w;
      syr0[8]=s2.x; syr0[9]=s2.y; syr0[10]=s2.z; syr0[11]=s2.w;
      float4 t0 = *reinterpret_cast<const float4*>(&syrow[SYC(c1)]);
      float4 t1 = *reinterpret_cast<const float4*>(&syrow[SYC(c1+4)]);
      float4 t2 = *reinterpret_cast<const float4*>(&syrow[SYC(c1+8)]);
      syr1[0]=t0.x; syr1[1]=t0.y; syr1[2]=t0.z; syr1[3]=t0.w;
      syr1[4]=t1.x; syr1[5]=t1.y; syr1[6]=t1.z; syr1[7]=t1.w;
      syr1[8]=t2.x; syr1[9]=t2.y; syr1[10]=t2.z; syr1[11]=t2.w;
    }
#pragma unroll
    for (int kk = 0; kk < 3; kk++) {
      const unsigned short* wp = wbase + (size_t)(ciq*3 + kk)*12288;
      v4f acc0 = {0.f, 0.f, 0.f, 0.f};
      v4f acc1 = {0.f, 0.f, 0.f, 0.f};
#pragma unroll
      for (int ks = 0; ks < 6; ks++) {
        v8s a = *reinterpret_cast<const v8s*>(wp + ks*512);
        acc0 = __builtin_amdgcn_mfma_f32_16x16x32_bf16(a, bfrA[ks], acc0, 0, 0, 0);
        acc1 = __builtin_amdgcn_mfma_f32_16x16x32_bf16(a, bfrB[ks], acc1, 0, 0, 0);
      }
      float4 kb4 = *reinterpret_cast<const float4*>(kbbase + (ciq*3 + kk)*64);
#pragma unroll
      for (int r = 0; r < 4; r++) {
        float k0 = acc0[r] + ((const float*)&kb4)[r];
        float k1 = acc1[r] + ((const float*)&kb4)[r];
#pragma unroll
        for (int s = 0; s < 8; s++) {
          o0[r][s] = fmaf(k0, syr0[kk + s], o0[r][s]);
          o1[r][s] = fmaf(k1, syr1[kk + s], o1[r][s]);
        }
      }
    }
  }

  EPILOGUE(0, o0)
  EPILOGUE(1, o1)
}

// ---------------------------------------------------------------- launcher
extern "C" void kernel_launch(void* const* d_in, const int* in_sizes, int n_in,
                              void* d_out, int out_size, void* d_ws, size_t ws_size,
                              hipStream_t stream) {
  const float* x     = (const float*)d_in[0];
  const float* ad    = (const float*)d_in[1];
  const float* c     = (const float*)d_in[2];
  const float* ne    = (const float*)d_in[3];
  const float* fw    = (const float*)d_in[4];
  const float* fb    = (const float*)d_in[5];
  const float* upw   = (const float*)d_in[6];
  const float* convw = (const float*)d_in[7];
  const float* kinw  = (const float*)d_in[8];
  const float* kinb  = (const float*)d_in[9];
  const float* krw1  = (const float*)d_in[10];
  const float* krb1  = (const float*)d_in[11];
  const float* krw2  = (const float*)d_in[12];
  const float* krb2  = (const float*)d_in[13];
  const float* kkw   = (const float*)d_in[14];
  const float* kkb   = (const float*)d_in[15];
  const float* kbw   = (const float*)d_in[16];
  const float* kbb   = (const float*)d_in[17];
  float* h = (float*)d_out;

  float* ws = (float*)d_ws;
  float* cond   = ws; ws += B_*COND_*LMEL_;
  float* hkpa   = ws; ws += B_*HID_*LMEL_;
  float* hkpb   = ws; ws += B_*HID_*LMEL_;
  float* biasb  = ws; ws += B_*BCH_*LMEL_;
  float* y2     = ws; ws += B_*C_*LAUD_;
  float* kbt    = ws; ws += KCH_;
  float* wtup   = ws; ws += C_*C_*16;
  float* kinwT  = ws; ws += HID_*COND_*5;
  float* krw1T  = ws; ws += 3*HID_*HID_*3;
  float* krw2T  = ws; ws += 3*HID_*HID_*3;
  float* kbwT   = ws; ws += BCH_*HID_*3;
  float* convwT = ws; ws += LAYERS_*C_*C_*3;
  unsigned short* waf = (unsigned short*)ws; ws += (KCH_*HID_*KPK_)/2;

  k_mkA<<<(KCH_*HID_*KPK_ + 255)/256, 256, 0, stream>>>(kkw, waf);
  k_mkKbT<<<(KCH_ + 255)/256, 256, 0, stream>>>(kkb, kbt);
  k_mkUp<<<(C_*C_*16 + 255)/256, 256, 0, stream>>>(upw, wtup);
  k_mkWTs<<<(HID_*COND_*5 + 255)/256, 256, 0, stream>>>(kinw, kinwT, 1, HID_, COND_*5);
  k_mkWTs<<<(3*HID_*HID_*3 + 255)/256, 256, 0, stream>>>(krw1, krw1T, 3, HID_, HID_*3);
  k_mkWTs<<<(3*HID_*HID_*3 + 255)/256, 256, 0, stream>>>(krw2, krw2T, 3, HID_, HID_*3);
  k_mkWTs<<<(BCH_*HID_*3 + 255)/256, 256, 0, stream>>>(kbw, kbwT, 1, BCH_, HID_*3);
  k_mkWTs<<<(LAYERS_*C_*C_*3 + 255)/256, 256, 0, stream>>>(convw, convwT, LAYERS_, C_, C_*3);

  k_noise_cond<<<B_*COND_, 256, 0, stream>>>(ne, fw, fb, c, cond);
  k_kp_in<<<B_*(LMEL_/32), 256, 0, stream>>>(cond, kinwT, kinb, hkpa);
  // res chain: a -> b -> a -> b  (final in hkpb)
  k_kp_res2<<<B_*(LMEL_/32), 256, 0, stream>>>(hkpa, krw1T + 0*HID_*HID_*3, krb1 + 0*HID_,
                                               krw2T + 0*HID_*HID_*3, krb2 + 0*HID_, hkpb);
  k_kp_res2<<<B_*(LMEL_/32), 256, 0, stream>>>(hkpb, krw1T + 1*HID_*HID_*3, krb1 + 1*HID_,
                                               krw2T + 1*HID_*HID_*3, krb2 + 1*HID_, hkpa);
  k_kp_res2<<<B_*(LMEL_/32), 256, 0, stream>>>(hkpa, krw1T + 2*HID_*HID_*3, krb1 + 2*HID_,
                                               krw2T + 2*HID_*HID_*3, krb2 + 2*HID_, hkpb);
  k_kp_bias<<<B_*(LMEL_/16), 256, 0, stream>>>(hkpb, kbwT, kbb, biasb);
  k_upsample<<<B_*65, 256, 0, stream>>>(x, wtup, h);

  for (int i = 0; i < LAYERS_; i++) {
    const float* wci = convwT + i*C_*C_*3;
    switch (i) {
      case 0: k_dilconv<1 ><<<B_*(LAUD_/128), 256, 0, stream>>>(h, ad, wci, y2); break;
      case 1: k_dilconv<3 ><<<B_*(LAUD_/128), 256, 0, stream>>>(h, ad, wci, y2); break;
      case 2: k_dilconv<9 ><<<B_*(LAUD_/128), 256, 0, stream>>>(h, ad, wci, y2); break;
      case 3: k_dilconv<27><<<B_*(LAUD_/128), 256, 0, stream>>>(h, ad, wci, y2); break;
    }
    k_lvc_mfma<<<B_*(LMEL_/FR2), 1024, 0, stream>>>(hkpb, waf, kbt, biasb, y2, ad, h, i);
  }
}

// Round 6
// 1061.592 us; speedup vs baseline: 1.0218x; 1.0218x over previous
//
#include <hip/hip_runtime.h>
#include <math.h>

#define B_      4
#define C_      32
#define COND_   80
#define LMEL_   2048
#define HOP_    8
#define UP_     8
#define LAYERS_ 4
#define K_      3
#define HID_    64
#define KPK_    3
#define EMB_    512
#define LAUD_   (LMEL_*UP_)          // 16384
#define KCH_    (LAYERS_*C_*2*C_*K_) // 24576
#define BCH_    (LAYERS_*2*C_)       // 256

typedef short v8s __attribute__((ext_vector_type(8)));
typedef float v4f __attribute__((ext_vector_type(4)));

__device__ __forceinline__ float lrelu_(float v, float s) { return v >= 0.f ? v : s * v; }

__device__ __forceinline__ unsigned short f2bf(float f) {  // RNE float->bf16
  unsigned int x = __float_as_uint(f);
  unsigned int r = (x + 0x7FFFu + ((x >> 16) & 1u)) >> 16;
  return (unsigned short)r;
}

// ---------------------------------------------------------------- prep: generic slab transpose src[s][oc][ick] -> dst[s][ick][oc]
__global__ void k_mkWTs(const float* __restrict__ src, float* __restrict__ dst,
                        int S, int OC, int ICK) {
  int idx = blockIdx.x*256 + threadIdx.x;
  if (idx >= S*OC*ICK) return;
  int s = idx / (OC*ICK), rem = idx % (OC*ICK);
  int oc = rem / ICK, ick = rem % ICK;
  dst[s*OC*ICK + ick*OC + oc] = src[idx];
}

// ---------------------------------------------------------------- K1: noise + condition
__global__ void k_noise_cond(const float* __restrict__ ne, const float* __restrict__ fw,
                             const float* __restrict__ fb, const float* __restrict__ c,
                             float* __restrict__ cond) {
  int b = blockIdx.x / COND_;
  int cc = blockIdx.x % COND_;
  __shared__ float red[256];
  float p = 0.f;
  for (int j = threadIdx.x; j < EMB_; j += 256)
    p += ne[b*EMB_ + j] * fw[cc*EMB_ + j];
  red[threadIdx.x] = p;
  __syncthreads();
  for (int s = 128; s > 0; s >>= 1) {
    if (threadIdx.x < s) red[threadIdx.x] += red[threadIdx.x + s];
    __syncthreads();
  }
  float noise = red[0] + fb[cc];
  const float* cp = c + (b*COND_ + cc)*LMEL_;
  float* op = cond + (b*COND_ + cc)*LMEL_;
  for (int l = threadIdx.x; l < LMEL_; l += 256) op[l] = cp[l] + noise;
}

// ---------------------------------------------------------------- K2: KP input conv (80->64, k=5, pad=2, lrelu 0.1), T=32, wT[(cc*5+k)*64+ch]
__global__ __launch_bounds__(256) void k_kp_in(const float* __restrict__ cond, const float* __restrict__ wT,
                                               const float* __restrict__ bias, float* __restrict__ out) {
  const int T = 32;
  int b  = blockIdx.x / (LMEL_/T);
  int lb = (blockIdx.x % (LMEL_/T)) * T;
  __shared__ float sc[COND_][T + 4];
  for (int idx = threadIdx.x; idx < COND_*(T+4); idx += 256) {
    int cc = idx / (T+4), j = idx % (T+4);
    int l = lb + j - 2;
    sc[cc][j] = (l >= 0 && l < LMEL_) ? cond[(b*COND_ + cc)*LMEL_ + l] : 0.f;
  }
  __syncthreads();
  int ch = threadIdx.x & 63;
  int lq = threadIdx.x >> 6;  // 0..3, 8 l's each
  float acc[8];
#pragma unroll
  for (int ii = 0; ii < 8; ii++) acc[ii] = bias[ch];
  for (int cc = 0; cc < COND_; cc++) {
    float r[12];
#pragma unroll
    for (int j = 0; j < 12; j++) r[j] = sc[cc][lq*8 + j];
#pragma unroll
    for (int k = 0; k < 5; k++) {
      float wv = wT[(cc*5 + k)*64 + ch];
#pragma unroll
      for (int ii = 0; ii < 8; ii++) acc[ii] = fmaf(wv, r[ii + k], acc[ii]);
    }
  }
  float* op = out + (b*HID_ + ch)*LMEL_ + lb + lq*8;
#pragma unroll
  for (int ii = 0; ii < 8; ii++) acc[ii] = lrelu_(acc[ii], 0.1f);
  *reinterpret_cast<float4*>(&op[0]) = make_float4(acc[0], acc[1], acc[2], acc[3]);
  *reinterpret_cast<float4*>(&op[4]) = make_float4(acc[4], acc[5], acc[6], acc[7]);
}

// ---------------------------------------------------------------- K3: fused res pair: out = in + lrelu(conv2(lrelu(conv1(in))))
__global__ __launch_bounds__(256) void k_kp_res2(const float* __restrict__ in,
                                                 const float* __restrict__ w1T, const float* __restrict__ b1,
                                                 const float* __restrict__ w2T, const float* __restrict__ b2,
                                                 float* __restrict__ out) {
  const int T = 32;
  int b  = blockIdx.x / (LMEL_/T);
  int lb = (blockIdx.x % (LMEL_/T)) * T;
  __shared__ float si[HID_][38];   // cols lb-2 .. lb+33 (36 used)
  __shared__ float sr[HID_][38];   // intermediate r, cols lb-1 .. lb+32 (34 used)
  for (int idx = threadIdx.x; idx < HID_*36; idx += 256) {
    int cc = idx / 36, j = idx % 36;
    int l = lb - 2 + j;
    si[cc][j] = (l >= 0 && l < LMEL_) ? in[(b*HID_ + cc)*LMEL_ + l] : 0.f;
  }
  __syncthreads();
  int ch = threadIdx.x & 63;
  int lq = threadIdx.x >> 6;   // 0..3
  {
    float b1v = b1[ch];
    float a1[9];
#pragma unroll
    for (int jj = 0; jj < 9; jj++) a1[jj] = b1v;
    for (int cc = 0; cc < HID_; cc++) {
      float r[11];
#pragma unroll
      for (int j = 0; j < 11; j++) r[j] = si[cc][lq*9 + j];
#pragma unroll
      for (int k = 0; k < 3; k++) {
        float wv = w1T[(cc*3 + k)*64 + ch];
#pragma unroll
        for (int jj = 0; jj < 9; jj++) a1[jj] = fmaf(wv, r[jj + k], a1[jj]);
      }
    }
#pragma unroll
    for (int jj = 0; jj < 9; jj++) {
      int m = lq*9 + jj;
      if (m < 34) sr[ch][m] = lrelu_(a1[jj], 0.1f);
    }
  }
  __syncthreads();
  {
    float b2v = b2[ch];
    float a2[8];
#pragma unroll
    for (int jj = 0; jj < 8; jj++) a2[jj] = b2v;
    for (int cc = 0; cc < HID_; cc++) {
      float r[10];
#pragma unroll
      for (int j = 0; j < 10; j++) r[j] = sr[cc][lq*8 + j];
#pragma unroll
      for (int k = 0; k < 3; k++) {
        float wv = w2T[(cc*3 + k)*64 + ch];
#pragma unroll
        for (int jj = 0; jj < 8; jj++) a2[jj] = fmaf(wv, r[jj + k], a2[jj]);
      }
    }
    float* op = out + (b*HID_ + ch)*LMEL_ + lb + lq*8;
    float v[8];
#pragma unroll
    for (int jj = 0; jj < 8; jj++)
      v[jj] = si[ch][lq*8 + jj + 2] + lrelu_(a2[jj], 0.1f);
    *reinterpret_cast<float4*>(&op[0]) = make_float4(v[0], v[1], v[2], v[3]);
    *reinterpret_cast<float4*>(&op[4]) = make_float4(v[4], v[5], v[6], v[7]);
  }
}

// ---------------------------------------------------------------- K4: bias conv (64->256, k=3, pad=1), T=16, wT[(cc*3+k)*256+ch]
__global__ __launch_bounds__(256) void k_kp_bias(const float* __restrict__ in, const float* __restrict__ wT,
                                                 const float* __restrict__ bias, float* __restrict__ out) {
  const int T = 16;
  int b  = blockIdx.x / (LMEL_/T);
  int lb = (blockIdx.x % (LMEL_/T)) * T;
  __shared__ float si[HID_][T + 2];
  for (int idx = threadIdx.x; idx < HID_*(T+2); idx += 256) {
    int cc = idx / (T+2), j = idx % (T+2);
    int l = lb + j - 1;
    si[cc][j] = (l >= 0 && l < LMEL_) ? in[(b*HID_ + cc)*LMEL_ + l] : 0.f;
  }
  __syncthreads();
  int ch = threadIdx.x;  // 0..255
  float acc[T];
  float bv = bias[ch];
#pragma unroll
  for (int ii = 0; ii < T; ii++) acc[ii] = bv;
  for (int cc = 0; cc < HID_; cc++) {
    float w0 = wT[(cc*3 + 0)*256 + ch];
    float w1 = wT[(cc*3 + 1)*256 + ch];
    float w2 = wT[(cc*3 + 2)*256 + ch];
#pragma unroll
    for (int ii = 0; ii < T; ii++)
      acc[ii] = fmaf(w0, si[cc][ii], fmaf(w1, si[cc][ii+1], fmaf(w2, si[cc][ii+2], acc[ii])));
  }
  float* op = out + (b*BCH_ + ch)*LMEL_ + lb;
#pragma unroll
  for (int q = 0; q < 4; q++)
    *reinterpret_cast<float4*>(&op[q*4]) = make_float4(acc[q*4], acc[q*4+1], acc[q*4+2], acc[q*4+3]);
}

// ---------------------------------------------------------------- prep: upsample weight transpose -> wt[(ci*16+j)*32+co]
__global__ void k_mkUp(const float* __restrict__ upw, float* __restrict__ wt) {
  int idx = blockIdx.x*256 + threadIdx.x;
  if (idx >= C_*C_*16) return;
  int co = idx & 31, j = (idx >> 5) & 15, ci = idx >> 9;
  wt[idx] = upw[(ci*C_ + co)*16 + j];
}

// ---------------------------------------------------------------- K5: upsample (conv_transpose1d stride 8, k=16, pad=4), lrelu(x,0.2) input
#define UT 32
__global__ __launch_bounds__(256) void k_upsample(const float* __restrict__ x, const float* __restrict__ wt,
                                                  float* __restrict__ h) {
  int b  = blockIdx.x / 65;
  int s0 = (blockIdx.x % 65) * UT;
  __shared__ float sw[16384];          // [ci][j][co]
  __shared__ float sx[C_][33 + 3];
  for (int idx = threadIdx.x*4; idx < 16384; idx += 1024)
    *reinterpret_cast<float4*>(&sw[idx]) = *reinterpret_cast<const float4*>(&wt[idx]);
  for (int idx = threadIdx.x; idx < C_*33; idx += 256) {
    int ci = idx / 33, i = idx % 33;
    int s = s0 - 1 + i;
    float v = (s >= 0 && s < LMEL_) ? x[(b*C_ + ci)*LMEL_ + s] : 0.f;
    sx[ci][i] = lrelu_(v, 0.2f);
  }
  __syncthreads();
  int co = threadIdx.x & 31, sq = threadIdx.x >> 5;  // sq 0..7, 4 frames each
  float acc[4][8];
#pragma unroll
  for (int k = 0; k < 4; k++)
#pragma unroll
    for (int r = 0; r < 8; r++) acc[k][r] = 0.f;
  for (int ci = 0; ci < C_; ci++) {
    float xv[5];
#pragma unroll
    for (int m = 0; m < 5; m++) xv[m] = sx[ci][sq*4 + m];
    const float* wl = &sw[ci*512 + co];
#pragma unroll
    for (int r = 0; r < 8; r++) {
      float wa = wl[r*32];
      float wb = wl[(r+8)*32];
#pragma unroll
      for (int k = 0; k < 4; k++)
        acc[k][r] = fmaf(wa, xv[k+1], fmaf(wb, xv[k], acc[k][r]));
    }
  }
  float* op = h + ((size_t)b*C_ + co)*LAUD_;
#pragma unroll
  for (int k = 0; k < 4; k++) {
    int s1 = s0 + sq*4 + k;
    int lo = 8*s1 - 4;
    if (lo >= 0 && lo + 4 <= LAUD_)
      *reinterpret_cast<float4*>(&op[lo]) = make_float4(acc[k][0], acc[k][1], acc[k][2], acc[k][3]);
    if (lo >= -4 && lo + 8 <= LAUD_)
      *reinterpret_cast<float4*>(&op[lo+4]) = make_float4(acc[k][4], acc[k][5], acc[k][6], acc[k][7]);
  }
}

// ---------------------------------------------------------------- prep: A-fragment-ordered bf16 weights
__global__ void k_mkA(const float* __restrict__ kw, unsigned short* __restrict__ waf) {
  int idx = blockIdx.x*256 + threadIdx.x;
  if (idx >= KCH_*HID_*KPK_) return;   // 4,718,592
  int i    = idx & 7;
  int lane = (idx >> 3) & 63;
  int ks   = (idx >> 9) % 6;
  int tile = (idx / 3072) & 3;
  int rk   = idx / 12288;              // 0..383
  int layer = rk / 96, rem = rk % 96, ci = rem / 3, kk = rem % 3;
  int cout = tile*16 + (lane & 15);
  int j    = ks*32 + ((lane >> 4) << 3) + i;
  int row  = ((layer*32 + ci)*64 + cout)*3 + kk;
  waf[idx] = f2bf(kw[row*192 + j]);
}

// ---------------------------------------------------------------- prep: kernel-conv bias reordered
__global__ void k_mkKbT(const float* __restrict__ kb, float* __restrict__ kbt) {
  int idx = blockIdx.x*256 + threadIdx.x;
  if (idx >= KCH_) return;             // 24576
  int cr = idx & 15, tile = (idx >> 4) & 3, rk = idx >> 6;
  int layer = rk / 96, rem = rk % 96, ci = rem / 3, kk = rem % 3;
  int cout = tile*16 + cr;
  kbt[idx] = kb[((layer*32 + ci)*64 + cout)*3 + kk];
}

// ---------------------------------------------------------------- K6: dilated conv (32->32, k=3) on lrelu(h+ad,0.2), out lrelu 0.2, T=128
template<int DIL>
__global__ __launch_bounds__(256) void k_dilconv(const float* __restrict__ h, const float* __restrict__ ad,
                                                 const float* __restrict__ wT, float* __restrict__ y2) {
  const int T = 128;
  int b  = blockIdx.x / (LAUD_/T);
  int tb = (blockIdx.x % (LAUD_/T)) * T;
  const int W = T + 2*DIL;
  __shared__ float ss[C_][T + 2*27 + 4];
  for (int idx = threadIdx.x; idx < C_*W; idx += 256) {
    int ci = idx / W, j = idx % W;
    int t = tb - DIL + j;
    float v = 0.f;
    if (t >= 0 && t < LAUD_) {
      int g = (b*C_ + ci)*LAUD_ + t;
      v = h[g] + ad[g];
    }
    ss[ci][j] = lrelu_(v, 0.2f);
  }
  __syncthreads();
  int co = threadIdx.x & 31, tq = threadIdx.x >> 5;
  float acc[16];
#pragma unroll
  for (int ii = 0; ii < 16; ii++) acc[ii] = 0.f;
  for (int ci = 0; ci < C_; ci++) {
    float w0 = wT[(ci*3 + 0)*32 + co];
    float w1 = wT[(ci*3 + 1)*32 + co];
    float w2 = wT[(ci*3 + 2)*32 + co];
#pragma unroll
    for (int ii = 0; ii < 16; ii++) {
      int tl = tq*16 + ii;
      acc[ii] = fmaf(w0, ss[ci][tl], fmaf(w1, ss[ci][tl + DIL], fmaf(w2, ss[ci][tl + 2*DIL], acc[ii])));
    }
  }
  float* op = y2 + (b*C_ + co)*LAUD_ + tb + tq*16;
#pragma unroll
  for (int ii = 0; ii < 16; ii++) acc[ii] = lrelu_(acc[ii], 0.2f);
#pragma unroll
  for (int q = 0; q < 4; q++)
    *reinterpret_cast<float4*>(&op[q*4]) = make_float4(acc[q*4], acc[q*4+1], acc[q*4+2], acc[q*4+3]);
}

// ---------------------------------------------------------------- K7: MFMA-fused KP-GEMM + LVC + gate + h update
// 512 thr, 8 waves = wq(0..3 ci-quarters) x tp(0..1). Block owns tiles {variant, variant+2}
// (a sigmoid/tanh pair). Grid = B * 64 ftiles * 2 variants = 512 blocks -> 2 blocks/CU.
// sy skewed (col += 4*(col>>5)); red aliases sy pool (sync-separated).
#define FR2 32
#define SYC(c) ((c) + (((c) >> 5) << 2))
#define RED(t, l, rs) pool[(((t)*64 + (l))*33) + (rs)]

#define EPILOGUE(G, OO)                                                          \
  {                                                                              \
    __syncthreads();                                                             \
    if (wq == 3) {                                                               \
      _Pragma("unroll") for (int r = 0; r < 4; r++)                              \
        _Pragma("unroll") for (int s = 0; s < 8; s++)                            \
          RED(tp, lane, r*8 + s) = OO[r][s];                                     \
    }                                                                            \
    __syncthreads();                                                             \
    if (wq == 2) {                                                               \
      _Pragma("unroll") for (int r = 0; r < 4; r++)                              \
        _Pragma("unroll") for (int s = 0; s < 8; s++)                            \
          RED(tp, lane, r*8 + s) += OO[r][s];                                    \
    }                                                                            \
    __syncthreads();                                                             \
    if (wq == 1) {                                                               \
      _Pragma("unroll") for (int r = 0; r < 4; r++)                              \
        _Pragma("unroll") for (int s = 0; s < 8; s++)                            \
          RED(tp, lane, r*8 + s) += OO[r][s];                                    \
    }                                                                            \
    __syncthreads();                                                             \
    if (wq == 0) {                                                               \
      _Pragma("unroll") for (int r = 0; r < 4; r++) {                            \
        int cout = tile*16 + ((lane >> 4) << 2) + r;                             \
        float bv = biasb[((size_t)b*BCH_ + layer*2*C_ + cout)*LMEL_ + l0 + G*16 + f]; \
        _Pragma("unroll") for (int s = 0; s < 8; s++)                            \
          OO[r][s] += RED(tp, lane, r*8 + s) + bv;                               \
      }                                                                          \
      if (tp == 1) {                                                             \
        _Pragma("unroll") for (int r = 0; r < 4; r++)                            \
          _Pragma("unroll") for (int s = 0; s < 8; s++)                          \
            RED(1, lane, r*8 + s) = OO[r][s];                                    \
      }                                                                          \
    }                                                                            \
    __syncthreads();                                                             \
    if (wq == 0 && tp == 0) {                                                    \
      _Pragma("unroll") for (int r = 0; r < 4; r++) {                            \
        int cout = tile*16 + ((lane >> 4) << 2) + r;                             \
        size_t base = ((size_t)b*C_ + cout)*LAUD_ + (size_t)(l0 + G*16 + f)*HOP_;\
        float4 h0 = *reinterpret_cast<const float4*>(&h[base]);                  \
        float4 h1 = *reinterpret_cast<const float4*>(&h[base + 4]);              \
        float4 a0 = *reinterpret_cast<const float4*>(&ad[base]);                 \
        float4 a1 = *reinterpret_cast<const float4*>(&ad[base + 4]);             \
        float outv[8];                                                           \
        _Pragma("unroll") for (int s = 0; s < 8; s++) {                          \
          float v  = OO[r][s];                                                   \
          float tv = RED(1, lane, r*8 + s);                                      \
          float sig = 1.f / (1.f + __expf(-v));                                  \
          float th  = 1.f - 2.f / (1.f + __expf(2.f*tv));                        \
          float hv = (s < 4) ? ((const float*)&h0)[s] : ((const float*)&h1)[s-4];\
          float av = (s < 4) ? ((const float*)&a0)[s] : ((const float*)&a1)[s-4];\
          outv[s] = hv + av + sig * th;                                          \
        }                                                                        \
        *reinterpret_cast<float4*>(&h[base])     = make_float4(outv[0], outv[1], outv[2], outv[3]); \
        *reinterpret_cast<float4*>(&h[base + 4]) = make_float4(outv[4], outv[5], outv[6], outv[7]); \
      }                                                                          \
    }                                                                            \
  }

__global__ __launch_bounds__(512, 4) void k_lvc_mfma(
    const float* __restrict__ hkp, const unsigned short* __restrict__ waf,
    const float* __restrict__ kbt, const float* __restrict__ biasb,
    const float* __restrict__ y2, const float* __restrict__ ad,
    float* __restrict__ h, int layer) {
  int b  = blockIdx.x >> 7;               // 64 frame-tiles x 2 variants
  int r7 = blockIdx.x & 127;
  int l0 = (r7 >> 1) * FR2;
  int variant = r7 & 1;

  __shared__ __align__(16) float pool[32*292];             // sy (skewed) / red alias
  __shared__ __align__(16) float shh[HID_][36];            // 34 used
  __shared__ __align__(16) unsigned short FB[2*6*64*8];    // B frags, 2 subtiles x 6 ksteps

  int tid = threadIdx.x;
  for (int idx = tid; idx < C_*(FR2*HOP_+2); idx += 512) {
    int ci = idx / (FR2*HOP_+2), j = idx % (FR2*HOP_+2);
    int t = l0*HOP_ - 1 + j;
    pool[ci*292 + SYC(j)] = (t >= 0 && t < LAUD_) ? y2[(b*C_ + ci)*LAUD_ + t] : 0.f;
  }
  for (int idx = tid; idx < HID_*34; idx += 512) {
    int hh = idx / 34, j = idx % 34;
    int l = l0 - 1 + j;
    shh[hh][j] = (l >= 0 && l < LMEL_) ? hkp[(b*HID_ + hh)*LMEL_ + l] : 0.f;
  }
  __syncthreads();
  for (int idx = tid; idx < 6144; idx += 512) {
    int i = idx & 7, lane2 = (idx >> 3) & 63, gk = idx >> 9;  // gk = g*6+ks
    int ks = gk % 6, g = gk / 6;
    int k = ks*32 + ((lane2 >> 4) << 3) + i;
    int col = lane2 & 15;
    int hh = k / 3, q = k - hh*3;
    FB[idx] = f2bf(shh[hh][g*16 + col + q]);
  }
  __syncthreads();

  int wave = tid >> 6, lane = tid & 63;
  int tp = wave & 1, wq = wave >> 1;      // tp: tile-pair member, wq: ci-quarter
  int tile = variant + 2*tp;              // {v, v+2}: sigmoid & tanh halves
  int f = lane & 15;

  v8s bfrA[6], bfrB[6];
#pragma unroll
  for (int ks = 0; ks < 6; ks++) {
    bfrA[ks] = *reinterpret_cast<const v8s*>(&FB[(ks*64 + lane)*8]);
    bfrB[ks] = *reinterpret_cast<const v8s*>(&FB[((6 + ks)*64 + lane)*8]);
  }

  float o0[4][8], o1[4][8];
#pragma unroll
  for (int r = 0; r < 4; r++)
#pragma unroll
    for (int s = 0; s < 8; s++) { o0[r][s] = 0.f; o1[r][s] = 0.f; }

  const int rk0 = layer*96 + wq*24;       // 8 ci per quarter = 24 rk
  const unsigned short* wbase = waf + ((size_t)rk0*4 + tile)*3072 + lane*8;
  const float* kbbase = kbt + (rk0*4 + tile)*16 + ((lane >> 4) << 2);

  for (int ciq = 0; ciq < 8; ciq++) {
    int ci = wq*8 + ciq;
    const float* syrow = &pool[ci*292];
    float syr0[12], syr1[12];
    {
      int c0 = f*8, c1 = 128 + f*8;
      float4 s0 = *reinterpret_cast<const float4*>(&syrow[SYC(c0)]);
      float4 s1 = *reinterpret_cast<const float4*>(&syrow[SYC(c0+4)]);
      float4 s2 = *reinterpret_cast<const float4*>(&syrow[SYC(c0+8)]);
      syr0[0]=s0.x; syr0[1]=s0.y; syr0[2]=s0.z; syr0[3]=s0.w;
      syr0[4]=s1.x; syr0[5]=s1.y; syr0[6]=s1.z; syr0[7]=s1.w;
      syr0[8]=s2.x; syr0[9]=s2.y; syr0[10]=s2.z; syr0[11]=s2.w;
      float4 t0 = *reinterpret_cast<const float4*>(&syrow[SYC(c1)]);
      float4 t1 = *reinterpret_cast<const float4*>(&syrow[SYC(c1+4)]);
      float4 t2 = *reinterpret_cast<const float4*>(&syrow[SYC(c1+8)]);
      syr1[0]=t0.x; syr1[1]=t0.y; syr1[2]=t0.z; syr1[3]=t0.w;
      syr1[4]=t1.x; syr1[5]=t1.y; syr1[6]=t1.z; syr1[7]=t1.w;
      syr1[8]=t2.x; syr1[9]=t2.y; syr1[10]=t2.z; syr1[11]=t2.w;
    }
#pragma unroll
    for (int kk = 0; kk < 3; kk++) {
      const unsigned short* wp = wbase + (size_t)(ciq*3 + kk)*12288;
      v4f acc0 = {0.f, 0.f, 0.f, 0.f};
      v4f acc1 = {0.f, 0.f, 0.f, 0.f};
#pragma unroll
      for (int ks = 0; ks < 6; ks++) {
        v8s a = *reinterpret_cast<const v8s*>(wp + ks*512);
        acc0 = __builtin_amdgcn_mfma_f32_16x16x32_bf16(a, bfrA[ks], acc0, 0, 0, 0);
        acc1 = __builtin_amdgcn_mfma_f32_16x16x32_bf16(a, bfrB[ks], acc1, 0, 0, 0);
      }
      float4 kb4 = *reinterpret_cast<const float4*>(kbbase + (ciq*3 + kk)*64);
#pragma unroll
      for (int r = 0; r < 4; r++) {
        float k0 = acc0[r] + ((const float*)&kb4)[r];
        float k1 = acc1[r] + ((const float*)&kb4)[r];
#pragma unroll
        for (int s = 0; s < 8; s++) {
          o0[r][s] = fmaf(k0, syr0[kk + s], o0[r][s]);
          o1[r][s] = fmaf(k1, syr1[kk + s], o1[r][s]);
        }
      }
    }
  }

  EPILOGUE(0, o0)
  EPILOGUE(1, o1)
}

// ---------------------------------------------------------------- launcher
extern "C" void kernel_launch(void* const* d_in, const int* in_sizes, int n_in,
                              void* d_out, int out_size, void* d_ws, size_t ws_size,
                              hipStream_t stream) {
  const float* x     = (const float*)d_in[0];
  const float* ad    = (const float*)d_in[1];
  const float* c     = (const float*)d_in[2];
  const float* ne    = (const float*)d_in[3];
  const float* fw    = (const float*)d_in[4];
  const float* fb    = (const float*)d_in[5];
  const float* upw   = (const float*)d_in[6];
  const float* convw = (const float*)d_in[7];
  const float* kinw  = (const float*)d_in[8];
  const float* kinb  = (const float*)d_in[9];
  const float* krw1  = (const float*)d_in[10];
  const float* krb1  = (const float*)d_in[11];
  const float* krw2  = (const float*)d_in[12];
  const float* krb2  = (const float*)d_in[13];
  const float* kkw   = (const float*)d_in[14];
  const float* kkb   = (const float*)d_in[15];
  const float* kbw   = (const float*)d_in[16];
  const float* kbb   = (const float*)d_in[17];
  float* h = (float*)d_out;

  float* ws = (float*)d_ws;
  float* cond   = ws; ws += B_*COND_*LMEL_;
  float* hkpa   = ws; ws += B_*HID_*LMEL_;
  float* hkpb   = ws; ws += B_*HID_*LMEL_;
  float* biasb  = ws; ws += B_*BCH_*LMEL_;
  float* y2     = ws; ws += B_*C_*LAUD_;
  float* kbt    = ws; ws += KCH_;
  float* wtup   = ws; ws += C_*C_*16;
  float* kinwT  = ws; ws += HID_*COND_*5;
  float* krw1T  = ws; ws += 3*HID_*HID_*3;
  float* krw2T  = ws; ws += 3*HID_*HID_*3;
  float* kbwT   = ws; ws += BCH_*HID_*3;
  float* convwT = ws; ws += LAYERS_*C_*C_*3;
  unsigned short* waf = (unsigned short*)ws; ws += (KCH_*HID_*KPK_)/2;

  k_mkA<<<(KCH_*HID_*KPK_ + 255)/256, 256, 0, stream>>>(kkw, waf);
  k_mkKbT<<<(KCH_ + 255)/256, 256, 0, stream>>>(kkb, kbt);
  k_mkUp<<<(C_*C_*16 + 255)/256, 256, 0, stream>>>(upw, wtup);
  k_mkWTs<<<(HID_*COND_*5 + 255)/256, 256, 0, stream>>>(kinw, kinwT, 1, HID_, COND_*5);
  k_mkWTs<<<(3*HID_*HID_*3 + 255)/256, 256, 0, stream>>>(krw1, krw1T, 3, HID_, HID_*3);
  k_mkWTs<<<(3*HID_*HID_*3 + 255)/256, 256, 0, stream>>>(krw2, krw2T, 3, HID_, HID_*3);
  k_mkWTs<<<(BCH_*HID_*3 + 255)/256, 256, 0, stream>>>(kbw, kbwT, 1, BCH_, HID_*3);
  k_mkWTs<<<(LAYERS_*C_*C_*3 + 255)/256, 256, 0, stream>>>(convw, convwT, LAYERS_, C_, C_*3);

  k_noise_cond<<<B_*COND_, 256, 0, stream>>>(ne, fw, fb, c, cond);
  k_kp_in<<<B_*(LMEL_/32), 256, 0, stream>>>(cond, kinwT, kinb, hkpa);
  // res chain: a -> b -> a -> b  (final in hkpb)
  k_kp_res2<<<B_*(LMEL_/32), 256, 0, stream>>>(hkpa, krw1T + 0*HID_*HID_*3, krb1 + 0*HID_,
                                               krw2T + 0*HID_*HID_*3, krb2 + 0*HID_, hkpb);
  k_kp_res2<<<B_*(LMEL_/32), 256, 0, stream>>>(hkpb, krw1T + 1*HID_*HID_*3, krb1 + 1*HID_,
                                               krw2T + 1*HID_*HID_*3, krb2 + 1*HID_, hkpa);
  k_kp_res2<<<B_*(LMEL_/32), 256, 0, stream>>>(hkpa, krw1T + 2*HID_*HID_*3, krb1 + 2*HID_,
                                               krw2T + 2*HID_*HID_*3, krb2 + 2*HID_, hkpb);
  k_kp_bias<<<B_*(LMEL_/16), 256, 0, stream>>>(hkpb, kbwT, kbb, biasb);
  k_upsample<<<B_*65, 256, 0, stream>>>(x, wtup, h);

  for (int i = 0; i < LAYERS_; i++) {
    const float* wci = convwT + i*C_*C_*3;
    switch (i) {
      case 0: k_dilconv<1 ><<<B_*(LAUD_/128), 256, 0, stream>>>(h, ad, wci, y2); break;
      case 1: k_dilconv<3 ><<<B_*(LAUD_/128), 256, 0, stream>>>(h, ad, wci, y2); break;
      case 2: k_dilconv<9 ><<<B_*(LAUD_/128), 256, 0, stream>>>(h, ad, wci, y2); break;
      case 3: k_dilconv<27><<<B_*(LAUD_/128), 256, 0, stream>>>(h, ad, wci, y2); break;
    }
    k_lvc_mfma<<<B_*128, 512, 0, stream>>>(hkpb, waf, kbt, biasb, y2, ad, h, i);
  }
}

// Round 7
// 680.725 us; speedup vs baseline: 1.5935x; 1.5595x over previous
//
#include <hip/hip_runtime.h>
#include <math.h>

#define B_      4
#define C_      32
#define COND_   80
#define LMEL_   2048
#define HOP_    8
#define UP_     8
#define LAYERS_ 4
#define K_      3
#define HID_    64
#define KPK_    3
#define EMB_    512
#define LAUD_   (LMEL_*UP_)          // 16384
#define KCH_    (LAYERS_*C_*2*C_*K_) // 24576
#define BCH_    (LAYERS_*2*C_)       // 256

typedef short v8s __attribute__((ext_vector_type(8)));
typedef float v4f __attribute__((ext_vector_type(4)));

__device__ __forceinline__ float lrelu_(float v, float s) { return v >= 0.f ? v : s * v; }

__device__ __forceinline__ unsigned short f2bf(float f) {  // RNE float->bf16
  unsigned int x = __float_as_uint(f);
  unsigned int r = (x + 0x7FFFu + ((x >> 16) & 1u)) >> 16;
  return (unsigned short)r;
}

// ---------------------------------------------------------------- prep: generic slab transpose src[s][oc][ick] -> dst[s][ick][oc]
__global__ void k_mkWTs(const float* __restrict__ src, float* __restrict__ dst,
                        int S, int OC, int ICK) {
  int idx = blockIdx.x*256 + threadIdx.x;
  if (idx >= S*OC*ICK) return;
  int s = idx / (OC*ICK), rem = idx % (OC*ICK);
  int oc = rem / ICK, ick = rem % ICK;
  dst[s*OC*ICK + ick*OC + oc] = src[idx];
}

// ---------------------------------------------------------------- K1: noise + condition
__global__ void k_noise_cond(const float* __restrict__ ne, const float* __restrict__ fw,
                             const float* __restrict__ fb, const float* __restrict__ c,
                             float* __restrict__ cond) {
  int b = blockIdx.x / COND_;
  int cc = blockIdx.x % COND_;
  __shared__ float red[256];
  float p = 0.f;
  for (int j = threadIdx.x; j < EMB_; j += 256)
    p += ne[b*EMB_ + j] * fw[cc*EMB_ + j];
  red[threadIdx.x] = p;
  __syncthreads();
  for (int s = 128; s > 0; s >>= 1) {
    if (threadIdx.x < s) red[threadIdx.x] += red[threadIdx.x + s];
    __syncthreads();
  }
  float noise = red[0] + fb[cc];
  const float* cp = c + (b*COND_ + cc)*LMEL_;
  float* op = cond + (b*COND_ + cc)*LMEL_;
  for (int l = threadIdx.x; l < LMEL_; l += 256) op[l] = cp[l] + noise;
}

// ---------------------------------------------------------------- K2: KP input conv (80->64, k=5, pad=2, lrelu 0.1), T=32, wT[(cc*5+k)*64+ch]
__global__ __launch_bounds__(256) void k_kp_in(const float* __restrict__ cond, const float* __restrict__ wT,
                                               const float* __restrict__ bias, float* __restrict__ out) {
  const int T = 32;
  int b  = blockIdx.x / (LMEL_/T);
  int lb = (blockIdx.x % (LMEL_/T)) * T;
  __shared__ float sc[COND_][T + 4];
  for (int idx = threadIdx.x; idx < COND_*(T+4); idx += 256) {
    int cc = idx / (T+4), j = idx % (T+4);
    int l = lb + j - 2;
    sc[cc][j] = (l >= 0 && l < LMEL_) ? cond[(b*COND_ + cc)*LMEL_ + l] : 0.f;
  }
  __syncthreads();
  int ch = threadIdx.x & 63;
  int lq = threadIdx.x >> 6;  // 0..3, 8 l's each
  float acc[8];
#pragma unroll
  for (int ii = 0; ii < 8; ii++) acc[ii] = bias[ch];
  for (int cc = 0; cc < COND_; cc++) {
    float r[12];
#pragma unroll
    for (int j = 0; j < 12; j++) r[j] = sc[cc][lq*8 + j];
#pragma unroll
    for (int k = 0; k < 5; k++) {
      float wv = wT[(cc*5 + k)*64 + ch];
#pragma unroll
      for (int ii = 0; ii < 8; ii++) acc[ii] = fmaf(wv, r[ii + k], acc[ii]);
    }
  }
  float* op = out + (b*HID_ + ch)*LMEL_ + lb + lq*8;
#pragma unroll
  for (int ii = 0; ii < 8; ii++) acc[ii] = lrelu_(acc[ii], 0.1f);
  *reinterpret_cast<float4*>(&op[0]) = make_float4(acc[0], acc[1], acc[2], acc[3]);
  *reinterpret_cast<float4*>(&op[4]) = make_float4(acc[4], acc[5], acc[6], acc[7]);
}

// ---------------------------------------------------------------- K3: fused res pair: out = in + lrelu(conv2(lrelu(conv1(in))))
__global__ __launch_bounds__(256) void k_kp_res2(const float* __restrict__ in,
                                                 const float* __restrict__ w1T, const float* __restrict__ b1,
                                                 const float* __restrict__ w2T, const float* __restrict__ b2,
                                                 float* __restrict__ out) {
  const int T = 32;
  int b  = blockIdx.x / (LMEL_/T);
  int lb = (blockIdx.x % (LMEL_/T)) * T;
  __shared__ float si[HID_][38];   // cols lb-2 .. lb+33 (36 used)
  __shared__ float sr[HID_][38];   // intermediate r, cols lb-1 .. lb+32 (34 used)
  for (int idx = threadIdx.x; idx < HID_*36; idx += 256) {
    int cc = idx / 36, j = idx % 36;
    int l = lb - 2 + j;
    si[cc][j] = (l >= 0 && l < LMEL_) ? in[(b*HID_ + cc)*LMEL_ + l] : 0.f;
  }
  __syncthreads();
  int ch = threadIdx.x & 63;
  int lq = threadIdx.x >> 6;   // 0..3
  {
    float b1v = b1[ch];
    float a1[9];
#pragma unroll
    for (int jj = 0; jj < 9; jj++) a1[jj] = b1v;
    for (int cc = 0; cc < HID_; cc++) {
      float r[11];
#pragma unroll
      for (int j = 0; j < 11; j++) r[j] = si[cc][lq*9 + j];
#pragma unroll
      for (int k = 0; k < 3; k++) {
        float wv = w1T[(cc*3 + k)*64 + ch];
#pragma unroll
        for (int jj = 0; jj < 9; jj++) a1[jj] = fmaf(wv, r[jj + k], a1[jj]);
      }
    }
#pragma unroll
    for (int jj = 0; jj < 9; jj++) {
      int m = lq*9 + jj;
      if (m < 34) sr[ch][m] = lrelu_(a1[jj], 0.1f);
    }
  }
  __syncthreads();
  {
    float b2v = b2[ch];
    float a2[8];
#pragma unroll
    for (int jj = 0; jj < 8; jj++) a2[jj] = b2v;
    for (int cc = 0; cc < HID_; cc++) {
      float r[10];
#pragma unroll
      for (int j = 0; j < 10; j++) r[j] = sr[cc][lq*8 + j];
#pragma unroll
      for (int k = 0; k < 3; k++) {
        float wv = w2T[(cc*3 + k)*64 + ch];
#pragma unroll
        for (int jj = 0; jj < 8; jj++) a2[jj] = fmaf(wv, r[jj + k], a2[jj]);
      }
    }
    float* op = out + (b*HID_ + ch)*LMEL_ + lb + lq*8;
    float v[8];
#pragma unroll
    for (int jj = 0; jj < 8; jj++)
      v[jj] = si[ch][lq*8 + jj + 2] + lrelu_(a2[jj], 0.1f);
    *reinterpret_cast<float4*>(&op[0]) = make_float4(v[0], v[1], v[2], v[3]);
    *reinterpret_cast<float4*>(&op[4]) = make_float4(v[4], v[5], v[6], v[7]);
  }
}

// ---------------------------------------------------------------- K4: bias conv (64->256, k=3, pad=1), T=16, wT[(cc*3+k)*256+ch]
__global__ __launch_bounds__(256) void k_kp_bias(const float* __restrict__ in, const float* __restrict__ wT,
                                                 const float* __restrict__ bias, float* __restrict__ out) {
  const int T = 16;
  int b  = blockIdx.x / (LMEL_/T);
  int lb = (blockIdx.x % (LMEL_/T)) * T;
  __shared__ float si[HID_][T + 2];
  for (int idx = threadIdx.x; idx < HID_*(T+2); idx += 256) {
    int cc = idx / (T+2), j = idx % (T+2);
    int l = lb + j - 1;
    si[cc][j] = (l >= 0 && l < LMEL_) ? in[(b*HID_ + cc)*LMEL_ + l] : 0.f;
  }
  __syncthreads();
  int ch = threadIdx.x;  // 0..255
  float acc[T];
  float bv = bias[ch];
#pragma unroll
  for (int ii = 0; ii < T; ii++) acc[ii] = bv;
  for (int cc = 0; cc < HID_; cc++) {
    float w0 = wT[(cc*3 + 0)*256 + ch];
    float w1 = wT[(cc*3 + 1)*256 + ch];
    float w2 = wT[(cc*3 + 2)*256 + ch];
#pragma unroll
    for (int ii = 0; ii < T; ii++)
      acc[ii] = fmaf(w0, si[cc][ii], fmaf(w1, si[cc][ii+1], fmaf(w2, si[cc][ii+2], acc[ii])));
  }
  float* op = out + (b*BCH_ + ch)*LMEL_ + lb;
#pragma unroll
  for (int q = 0; q < 4; q++)
    *reinterpret_cast<float4*>(&op[q*4]) = make_float4(acc[q*4], acc[q*4+1], acc[q*4+2], acc[q*4+3]);
}

// ---------------------------------------------------------------- prep: upsample weight transpose -> wt[(ci*16+j)*32+co]
__global__ void k_mkUp(const float* __restrict__ upw, float* __restrict__ wt) {
  int idx = blockIdx.x*256 + threadIdx.x;
  if (idx >= C_*C_*16) return;
  int co = idx & 31, j = (idx >> 5) & 15, ci = idx >> 9;
  wt[idx] = upw[(ci*C_ + co)*16 + j];
}

// ---------------------------------------------------------------- K5: upsample (conv_transpose1d stride 8, k=16, pad=4), lrelu(x,0.2) input
#define UT 32
__global__ __launch_bounds__(256) void k_upsample(const float* __restrict__ x, const float* __restrict__ wt,
                                                  float* __restrict__ h) {
  int b  = blockIdx.x / 65;
  int s0 = (blockIdx.x % 65) * UT;
  __shared__ float sw[16384];          // [ci][j][co]
  __shared__ float sx[C_][33 + 3];
  for (int idx = threadIdx.x*4; idx < 16384; idx += 1024)
    *reinterpret_cast<float4*>(&sw[idx]) = *reinterpret_cast<const float4*>(&wt[idx]);
  for (int idx = threadIdx.x; idx < C_*33; idx += 256) {
    int ci = idx / 33, i = idx % 33;
    int s = s0 - 1 + i;
    float v = (s >= 0 && s < LMEL_) ? x[(b*C_ + ci)*LMEL_ + s] : 0.f;
    sx[ci][i] = lrelu_(v, 0.2f);
  }
  __syncthreads();
  int co = threadIdx.x & 31, sq = threadIdx.x >> 5;  // sq 0..7, 4 frames each
  float acc[4][8];
#pragma unroll
  for (int k = 0; k < 4; k++)
#pragma unroll
    for (int r = 0; r < 8; r++) acc[k][r] = 0.f;
  for (int ci = 0; ci < C_; ci++) {
    float xv[5];
#pragma unroll
    for (int m = 0; m < 5; m++) xv[m] = sx[ci][sq*4 + m];
    const float* wl = &sw[ci*512 + co];
#pragma unroll
    for (int r = 0; r < 8; r++) {
      float wa = wl[r*32];
      float wb = wl[(r+8)*32];
#pragma unroll
      for (int k = 0; k < 4; k++)
        acc[k][r] = fmaf(wa, xv[k+1], fmaf(wb, xv[k], acc[k][r]));
    }
  }
  float* op = h + ((size_t)b*C_ + co)*LAUD_;
#pragma unroll
  for (int k = 0; k < 4; k++) {
    int s1 = s0 + sq*4 + k;
    int lo = 8*s1 - 4;
    if (lo >= 0 && lo + 4 <= LAUD_)
      *reinterpret_cast<float4*>(&op[lo]) = make_float4(acc[k][0], acc[k][1], acc[k][2], acc[k][3]);
    if (lo >= -4 && lo + 8 <= LAUD_)
      *reinterpret_cast<float4*>(&op[lo+4]) = make_float4(acc[k][4], acc[k][5], acc[k][6], acc[k][7]);
  }
}

// ---------------------------------------------------------------- prep: A-fragment-ordered bf16 weights
__global__ void k_mkA(const float* __restrict__ kw, unsigned short* __restrict__ waf) {
  int idx = blockIdx.x*256 + threadIdx.x;
  if (idx >= KCH_*HID_*KPK_) return;   // 4,718,592
  int i    = idx & 7;
  int lane = (idx >> 3) & 63;
  int ks   = (idx >> 9) % 6;
  int tile = (idx / 3072) & 3;
  int rk   = idx / 12288;              // 0..383
  int layer = rk / 96, rem = rk % 96, ci = rem / 3, kk = rem % 3;
  int cout = tile*16 + (lane & 15);
  int j    = ks*32 + ((lane >> 4) << 3) + i;
  int row  = ((layer*32 + ci)*64 + cout)*3 + kk;
  waf[idx] = f2bf(kw[row*192 + j]);
}

// ---------------------------------------------------------------- prep: kernel-conv bias reordered
__global__ void k_mkKbT(const float* __restrict__ kb, float* __restrict__ kbt) {
  int idx = blockIdx.x*256 + threadIdx.x;
  if (idx >= KCH_) return;             // 24576
  int cr = idx & 15, tile = (idx >> 4) & 3, rk = idx >> 6;
  int layer = rk / 96, rem = rk % 96, ci = rem / 3, kk = rem % 3;
  int cout = tile*16 + cr;
  kbt[idx] = kb[((layer*32 + ci)*64 + cout)*3 + kk];
}

// ---------------------------------------------------------------- K6: dilated conv (32->32, k=3) on lrelu(h+ad,0.2), out lrelu 0.2, T=128
template<int DIL>
__global__ __launch_bounds__(256) void k_dilconv(const float* __restrict__ h, const float* __restrict__ ad,
                                                 const float* __restrict__ wT, float* __restrict__ y2) {
  const int T = 128;
  int b  = blockIdx.x / (LAUD_/T);
  int tb = (blockIdx.x % (LAUD_/T)) * T;
  const int W = T + 2*DIL;
  __shared__ float ss[C_][T + 2*27 + 4];
  for (int idx = threadIdx.x; idx < C_*W; idx += 256) {
    int ci = idx / W, j = idx % W;
    int t = tb - DIL + j;
    float v = 0.f;
    if (t >= 0 && t < LAUD_) {
      int g = (b*C_ + ci)*LAUD_ + t;
      v = h[g] + ad[g];
    }
    ss[ci][j] = lrelu_(v, 0.2f);
  }
  __syncthreads();
  int co = threadIdx.x & 31, tq = threadIdx.x >> 5;
  float acc[16];
#pragma unroll
  for (int ii = 0; ii < 16; ii++) acc[ii] = 0.f;
  for (int ci = 0; ci < C_; ci++) {
    float w0 = wT[(ci*3 + 0)*32 + co];
    float w1 = wT[(ci*3 + 1)*32 + co];
    float w2 = wT[(ci*3 + 2)*32 + co];
#pragma unroll
    for (int ii = 0; ii < 16; ii++) {
      int tl = tq*16 + ii;
      acc[ii] = fmaf(w0, ss[ci][tl], fmaf(w1, ss[ci][tl + DIL], fmaf(w2, ss[ci][tl + 2*DIL], acc[ii])));
    }
  }
  float* op = y2 + (b*C_ + co)*LAUD_ + tb + tq*16;
#pragma unroll
  for (int ii = 0; ii < 16; ii++) acc[ii] = lrelu_(acc[ii], 0.2f);
#pragma unroll
  for (int q = 0; q < 4; q++)
    *reinterpret_cast<float4*>(&op[q*4]) = make_float4(acc[q*4], acc[q*4+1], acc[q*4+2], acc[q*4+3]);
}

// ---------------------------------------------------------------- K7: MFMA-fused KP-GEMM + LVC + gate + h update
// 512 thr, 8 waves = wq(0..3 ci-quarters) x tp(0..1). Block owns tiles {variant, variant+2}
// (a sigmoid/tanh pair). Grid = B * 64 ftiles * 2 variants = 512 blocks -> 2 blocks/CU.
// launch_bounds min-waves MUST stay 2: (512,4) caps unified regs at 128, compiler splits
// 64 arch + 64 accum -> ~110-reg working set spills (r5/r6: WRITE_SIZE 380MB). At 108
// VGPRs the HW already runs 4 waves/SIMD; no bound needed to get 2 blocks/CU.
#define FR2 32
#define SYC(c) ((c) + (((c) >> 5) << 2))
#define RED(t, l, rs) pool[(((t)*64 + (l))*33) + (rs)]

#define EPILOGUE(G, OO)                                                          \
  {                                                                              \
    __syncthreads();                                                             \
    if (wq == 3) {                                                               \
      _Pragma("unroll") for (int r = 0; r < 4; r++)                              \
        _Pragma("unroll") for (int s = 0; s < 8; s++)                            \
          RED(tp, lane, r*8 + s) = OO[r][s];                                     \
    }                                                                            \
    __syncthreads();                                                             \
    if (wq == 2) {                                                               \
      _Pragma("unroll") for (int r = 0; r < 4; r++)                              \
        _Pragma("unroll") for (int s = 0; s < 8; s++)                            \
          RED(tp, lane, r*8 + s) += OO[r][s];                                    \
    }                                                                            \
    __syncthreads();                                                             \
    if (wq == 1) {                                                               \
      _Pragma("unroll") for (int r = 0; r < 4; r++)                              \
        _Pragma("unroll") for (int s = 0; s < 8; s++)                            \
          RED(tp, lane, r*8 + s) += OO[r][s];                                    \
    }                                                                            \
    __syncthreads();                                                             \
    if (wq == 0) {                                                               \
      _Pragma("unroll") for (int r = 0; r < 4; r++) {                            \
        int cout = tile*16 + ((lane >> 4) << 2) + r;                             \
        float bv = biasb[((size_t)b*BCH_ + layer*2*C_ + cout)*LMEL_ + l0 + G*16 + f]; \
        _Pragma("unroll") for (int s = 0; s < 8; s++)                            \
          OO[r][s] += RED(tp, lane, r*8 + s) + bv;                               \
      }                                                                          \
      if (tp == 1) {                                                             \
        _Pragma("unroll") for (int r = 0; r < 4; r++)                            \
          _Pragma("unroll") for (int s = 0; s < 8; s++)                          \
            RED(1, lane, r*8 + s) = OO[r][s];                                    \
      }                                                                          \
    }                                                                            \
    __syncthreads();                                                             \
    if (wq == 0 && tp == 0) {                                                    \
      _Pragma("unroll") for (int r = 0; r < 4; r++) {                            \
        int cout = tile*16 + ((lane >> 4) << 2) + r;                             \
        size_t base = ((size_t)b*C_ + cout)*LAUD_ + (size_t)(l0 + G*16 + f)*HOP_;\
        float4 h0 = *reinterpret_cast<const float4*>(&h[base]);                  \
        float4 h1 = *reinterpret_cast<const float4*>(&h[base + 4]);              \
        float4 a0 = *reinterpret_cast<const float4*>(&ad[base]);                 \
        float4 a1 = *reinterpret_cast<const float4*>(&ad[base + 4]);             \
        float outv[8];                                                           \
        _Pragma("unroll") for (int s = 0; s < 8; s++) {                          \
          float v  = OO[r][s];                                                   \
          float tv = RED(1, lane, r*8 + s);                                      \
          float sig = 1.f / (1.f + __expf(-v));                                  \
          float th  = 1.f - 2.f / (1.f + __expf(2.f*tv));                        \
          float hv = (s < 4) ? ((const float*)&h0)[s] : ((const float*)&h1)[s-4];\
          float av = (s < 4) ? ((const float*)&a0)[s] : ((const float*)&a1)[s-4];\
          outv[s] = hv + av + sig * th;                                          \
        }                                                                        \
        *reinterpret_cast<float4*>(&h[base])     = make_float4(outv[0], outv[1], outv[2], outv[3]); \
        *reinterpret_cast<float4*>(&h[base + 4]) = make_float4(outv[4], outv[5], outv[6], outv[7]); \
      }                                                                          \
    }                                                                            \
  }

__global__ __launch_bounds__(512, 2) void k_lvc_mfma(
    const float* __restrict__ hkp, const unsigned short* __restrict__ waf,
    const float* __restrict__ kbt, const float* __restrict__ biasb,
    const float* __restrict__ y2, const float* __restrict__ ad,
    float* __restrict__ h, int layer) {
  int b  = blockIdx.x >> 7;               // 64 frame-tiles x 2 variants
  int r7 = blockIdx.x & 127;
  int l0 = (r7 >> 1) * FR2;
  int variant = r7 & 1;

  __shared__ __align__(16) float pool[32*292];             // sy (skewed) / red alias
  __shared__ __align__(16) float shh[HID_][36];            // 34 used
  __shared__ __align__(16) unsigned short FB[2*6*64*8];    // B frags, 2 subtiles x 6 ksteps

  int tid = threadIdx.x;
  for (int idx = tid; idx < C_*(FR2*HOP_+2); idx += 512) {
    int ci = idx / (FR2*HOP_+2), j = idx % (FR2*HOP_+2);
    int t = l0*HOP_ - 1 + j;
    pool[ci*292 + SYC(j)] = (t >= 0 && t < LAUD_) ? y2[(b*C_ + ci)*LAUD_ + t] : 0.f;
  }
  for (int idx = tid; idx < HID_*34; idx += 512) {
    int hh = idx / 34, j = idx % 34;
    int l = l0 - 1 + j;
    shh[hh][j] = (l >= 0 && l < LMEL_) ? hkp[(b*HID_ + hh)*LMEL_ + l] : 0.f;
  }
  __syncthreads();
  for (int idx = tid; idx < 6144; idx += 512) {
    int i = idx & 7, lane2 = (idx >> 3) & 63, gk = idx >> 9;  // gk = g*6+ks
    int ks = gk % 6, g = gk / 6;
    int k = ks*32 + ((lane2 >> 4) << 3) + i;
    int col = lane2 & 15;
    int hh = k / 3, q = k - hh*3;
    FB[idx] = f2bf(shh[hh][g*16 + col + q]);
  }
  __syncthreads();

  int wave = tid >> 6, lane = tid & 63;
  int tp = wave & 1, wq = wave >> 1;      // tp: tile-pair member, wq: ci-quarter
  int tile = variant + 2*tp;              // {v, v+2}: sigmoid & tanh halves
  int f = lane & 15;

  v8s bfrA[6], bfrB[6];
#pragma unroll
  for (int ks = 0; ks < 6; ks++) {
    bfrA[ks] = *reinterpret_cast<const v8s*>(&FB[(ks*64 + lane)*8]);
    bfrB[ks] = *reinterpret_cast<const v8s*>(&FB[((6 + ks)*64 + lane)*8]);
  }

  float o0[4][8], o1[4][8];
#pragma unroll
  for (int r = 0; r < 4; r++)
#pragma unroll
    for (int s = 0; s < 8; s++) { o0[r][s] = 0.f; o1[r][s] = 0.f; }

  const int rk0 = layer*96 + wq*24;       // 8 ci per quarter = 24 rk
  const unsigned short* wbase = waf + ((size_t)rk0*4 + tile)*3072 + lane*8;
  const float* kbbase = kbt + (rk0*4 + tile)*16 + ((lane >> 4) << 2);

  for (int ciq = 0; ciq < 8; ciq++) {
    int ci = wq*8 + ciq;
    const float* syrow = &pool[ci*292];
    float syr0[12], syr1[12];
    {
      int c0 = f*8, c1 = 128 + f*8;
      float4 s0 = *reinterpret_cast<const float4*>(&syrow[SYC(c0)]);
      float4 s1 = *reinterpret_cast<const float4*>(&syrow[SYC(c0+4)]);
      float4 s2 = *reinterpret_cast<const float4*>(&syrow[SYC(c0+8)]);
      syr0[0]=s0.x; syr0[1]=s0.y; syr0[2]=s0.z; syr0[3]=s0.w;
      syr0[4]=s1.x; syr0[5]=s1.y; syr0[6]=s1.z; syr0[7]=s1.w;
      syr0[8]=s2.x; syr0[9]=s2.y; syr0[10]=s2.z; syr0[11]=s2.w;
      float4 t0 = *reinterpret_cast<const float4*>(&syrow[SYC(c1)]);
      float4 t1 = *reinterpret_cast<const float4*>(&syrow[SYC(c1+4)]);
      float4 t2 = *reinterpret_cast<const float4*>(&syrow[SYC(c1+8)]);
      syr1[0]=t0.x; syr1[1]=t0.y; syr1[2]=t0.z; syr1[3]=t0.w;
      syr1[4]=t1.x; syr1[5]=t1.y; syr1[6]=t1.z; syr1[7]=t1.w;
      syr1[8]=t2.x; syr1[9]=t2.y; syr1[10]=t2.z; syr1[11]=t2.w;
    }
#pragma unroll
    for (int kk = 0; kk < 3; kk++) {
      const unsigned short* wp = wbase + (size_t)(ciq*3 + kk)*12288;
      v4f acc0 = {0.f, 0.f, 0.f, 0.f};
      v4f acc1 = {0.f, 0.f, 0.f, 0.f};
#pragma unroll
      for (int ks = 0; ks < 6; ks++) {
        v8s a = *reinterpret_cast<const v8s*>(wp + ks*512);
        acc0 = __builtin_amdgcn_mfma_f32_16x16x32_bf16(a, bfrA[ks], acc0, 0, 0, 0);
        acc1 = __builtin_amdgcn_mfma_f32_16x16x32_bf16(a, bfrB[ks], acc1, 0, 0, 0);
      }
      float4 kb4 = *reinterpret_cast<const float4*>(kbbase + (ciq*3 + kk)*64);
#pragma unroll
      for (int r = 0; r < 4; r++) {
        float k0 = acc0[r] + ((const float*)&kb4)[r];
        float k1 = acc1[r] + ((const float*)&kb4)[r];
#pragma unroll
        for (int s = 0; s < 8; s++) {
          o0[r][s] = fmaf(k0, syr0[kk + s], o0[r][s]);
          o1[r][s] = fmaf(k1, syr1[kk + s], o1[r][s]);
        }
      }
    }
  }

  EPILOGUE(0, o0)
  EPILOGUE(1, o1)
}

// ---------------------------------------------------------------- launcher
extern "C" void kernel_launch(void* const* d_in, const int* in_sizes, int n_in,
                              void* d_out, int out_size, void* d_ws, size_t ws_size,
                              hipStream_t stream) {
  const float* x     = (const float*)d_in[0];
  const float* ad    = (const float*)d_in[1];
  const float* c     = (const float*)d_in[2];
  const float* ne    = (const float*)d_in[3];
  const float* fw    = (const float*)d_in[4];
  const float* fb    = (const float*)d_in[5];
  const float* upw   = (const float*)d_in[6];
  const float* convw = (const float*)d_in[7];
  const float* kinw  = (const float*)d_in[8];
  const float* kinb  = (const float*)d_in[9];
  const float* krw1  = (const float*)d_in[10];
  const float* krb1  = (const float*)d_in[11];
  const float* krw2  = (const float*)d_in[12];
  const float* krb2  = (const float*)d_in[13];
  const float* kkw   = (const float*)d_in[14];
  const float* kkb   = (const float*)d_in[15];
  const float* kbw   = (const float*)d_in[16];
  const float* kbb   = (const float*)d_in[17];
  float* h = (float*)d_out;

  float* ws = (float*)d_ws;
  float* cond   = ws; ws += B_*COND_*LMEL_;
  float* hkpa   = ws; ws += B_*HID_*LMEL_;
  float* hkpb   = ws; ws += B_*HID_*LMEL_;
  float* biasb  = ws; ws += B_*BCH_*LMEL_;
  float* y2     = ws; ws += B_*C_*LAUD_;
  float* kbt    = ws; ws += KCH_;
  float* wtup   = ws; ws += C_*C_*16;
  float* kinwT  = ws; ws += HID_*COND_*5;
  float* krw1T  = ws; ws += 3*HID_*HID_*3;
  float* krw2T  = ws; ws += 3*HID_*HID_*3;
  float* kbwT   = ws; ws += BCH_*HID_*3;
  float* convwT = ws; ws += LAYERS_*C_*C_*3;
  unsigned short* waf = (unsigned short*)ws; ws += (KCH_*HID_*KPK_)/2;

  k_mkA<<<(KCH_*HID_*KPK_ + 255)/256, 256, 0, stream>>>(kkw, waf);
  k_mkKbT<<<(KCH_ + 255)/256, 256, 0, stream>>>(kkb, kbt);
  k_mkUp<<<(C_*C_*16 + 255)/256, 256, 0, stream>>>(upw, wtup);
  k_mkWTs<<<(HID_*COND_*5 + 255)/256, 256, 0, stream>>>(kinw, kinwT, 1, HID_, COND_*5);
  k_mkWTs<<<(3*HID_*HID_*3 + 255)/256, 256, 0, stream>>>(krw1, krw1T, 3, HID_, HID_*3);
  k_mkWTs<<<(3*HID_*HID_*3 + 255)/256, 256, 0, stream>>>(krw2, krw2T, 3, HID_, HID_*3);
  k_mkWTs<<<(BCH_*HID_*3 + 255)/256, 256, 0, stream>>>(kbw, kbwT, 1, BCH_, HID_*3);
  k_mkWTs<<<(LAYERS_*C_*C_*3 + 255)/256, 256, 0, stream>>>(convw, convwT, LAYERS_, C_, C_*3);

  k_noise_cond<<<B_*COND_, 256, 0, stream>>>(ne, fw, fb, c, cond);
  k_kp_in<<<B_*(LMEL_/32), 256, 0, stream>>>(cond, kinwT, kinb, hkpa);
  // res chain: a -> b -> a -> b  (final in hkpb)
  k_kp_res2<<<B_*(LMEL_/32), 256, 0, stream>>>(hkpa, krw1T + 0*HID_*HID_*3, krb1 + 0*HID_,
                                               krw2T + 0*HID_*HID_*3, krb2 + 0*HID_, hkpb);
  k_kp_res2<<<B_*(LMEL_/32), 256, 0, stream>>>(hkpb, krw1T + 1*HID_*HID_*3, krb1 + 1*HID_,
                                               krw2T + 1*HID_*HID_*3, krb2 + 1*HID_, hkpa);
  k_kp_res2<<<B_*(LMEL_/32), 256, 0, stream>>>(hkpa, krw1T + 2*HID_*HID_*3, krb1 + 2*HID_,
                                               krw2T + 2*HID_*HID_*3, krb2 + 2*HID_, hkpb);
  k_kp_bias<<<B_*(LMEL_/16), 256, 0, stream>>>(hkpb, kbwT, kbb, biasb);
  k_upsample<<<B_*65, 256, 0, stream>>>(x, wtup, h);

  for (int i = 0; i < LAYERS_; i++) {
    const float* wci = convwT + i*C_*C_*3;
    switch (i) {
      case 0: k_dilconv<1 ><<<B_*(LAUD_/128), 256, 0, stream>>>(h, ad, wci, y2); break;
      case 1: k_dilconv<3 ><<<B_*(LAUD_/128), 256, 0, stream>>>(h, ad, wci, y2); break;
      case 2: k_dilconv<9 ><<<B_*(LAUD_/128), 256, 0, stream>>>(h, ad, wci, y2); break;
      case 3: k_dilconv<27><<<B_*(LAUD_/128), 256, 0, stream>>>(h, ad, wci, y2); break;
    }
    k_lvc_mfma<<<B_*128, 512, 0, stream>>>(hkpb, waf, kbt, biasb, y2, ad, h, i);
  }
}